// Round 1
// baseline (1072.736 us; speedup 1.0000x reference)
//
#include <hip/hip_runtime.h>
#include <math.h>

#define BB 8
#define CIN 256
#define HH 64
#define WW 64
#define HW 4096
#define COUT 256
#define KKT 9       // 3x3 taps
#define KTOT 2304   // CIN*9

// ws layout (floats): sy[B*9*HW] | sx[B*9*HW] | m[B*9*HW]
#define WS_N (BB*KKT*HW)   // 294912

// ---------------- Kernel 1: offset conv (256->27) + transform ----------------
// grid: (B*9*HW)/256 = 1152 blocks, 256 threads.
// Each block: fixed (b, jg); each thread: one pos, channels {jg, jg+9, jg+18}.
__global__ __launch_bounds__(256) void offconv_kernel(
    const float* __restrict__ x, const float* __restrict__ w_off,
    const float* __restrict__ b_off, float* __restrict__ ws)
{
  __shared__ float w_s[3 * KTOT];   // 27.6 KB

  const int tid = threadIdx.x;
  const int g0  = blockIdx.x * 256;
  const int t   = g0 >> 12;          // b*9 + jg (uniform per block)
  const int jg  = t % 9;
  const int b   = t / 9;
  const int pos = (g0 & 4095) + tid;
  const int ho  = pos >> 6, wo = pos & 63;

  // stage the 3 weight rows
  for (int q = tid; q < 3 * KTOT; q += 256) {
    int jj = q / KTOT, r = q - jj * KTOT;
    w_s[q] = w_off[(jg + 9 * jj) * KTOT + r];
  }
  __syncthreads();

  float a0 = b_off[jg], a1 = b_off[jg + 9], a2 = b_off[jg + 18];
  const float* xb = x + (size_t)b * CIN * HW;

  for (int c = 0; c < CIN; ++c) {
    const float* xc = xb + c * HW;
    const float* wc = w_s + c * 9;
#pragma unroll
    for (int t9 = 0; t9 < 9; ++t9) {
      int ky = t9 / 3, kx = t9 - 3 * ky;
      int yy = ho - 1 + ky, xx = wo - 1 + kx;
      bool ok = ((unsigned)yy < 64u) && ((unsigned)xx < 64u);
      float xv = ok ? xc[yy * 64 + xx] : 0.0f;
      a0 = fmaf(wc[t9],            xv, a0);
      a1 = fmaf(wc[KTOT + t9],     xv, a1);
      a2 = fmaf(wc[2 * KTOT + t9], xv, a2);
    }
  }

  // transform & store. j0=jg (<9 -> offset), j1=jg+9 (<18 -> offset), j2=jg+18 (mask)
  // offset channel j: kk=j>>1, d=j&1 (d==0 -> y, d==1 -> x)
  {
    int j = jg;
    int kk = j >> 1;
    if ((j & 1) == 0) ws[(b * 9 + kk) * HW + pos] = a0 + (float)(ho - 1 + kk / 3);
    else              ws[WS_N + (b * 9 + kk) * HW + pos] = a0 + (float)(wo - 1 + kk % 3);
  }
  {
    int j = jg + 9;
    int kk = j >> 1;
    if ((j & 1) == 0) ws[(b * 9 + kk) * HW + pos] = a1 + (float)(ho - 1 + kk / 3);
    else              ws[WS_N + (b * 9 + kk) * HW + pos] = a1 + (float)(wo - 1 + kk % 3);
  }
  {
    int kk = jg;  // j2-18
    ws[2 * WS_N + (b * 9 + kk) * HW + pos] = 1.0f / (1.0f + expf(-a2));
  }
}

// ---------------- Kernel 2: bilinear gather + 256x2304 GEMM ----------------
// grid: B * (HW/16) = 2048 blocks, 256 threads.
// block tile: 256 co x 16 pos; c-chunks of 4; thread = 4co x 4pos.
#define CC 4
__global__ __launch_bounds__(256) void dcn_kernel(
    const float* __restrict__ x, const float* __restrict__ w_dcn,
    const float* __restrict__ b_dcn, const float* __restrict__ ws,
    float* __restrict__ out)
{
  __shared__ float w_lds[36 * 256];   // [kidx=cl*9+kk][co]  36.9 KB
  __shared__ float v_lds[36 * 16];    // [kidx][p]
  __shared__ int   s_y0[144], s_x0[144];
  __shared__ float s_wy[144], s_wx[144], s_m[144];

  const int tid = threadIdx.x;
  const int bx  = blockIdx.x;
  const int b   = bx >> 8;
  const int pos0 = (bx & 255) * 16;

  // per-(kk,p) sampling params
  if (tid < 144) {
    int kk = tid >> 4, p = tid & 15;
    int pos = pos0 + p;
    float sy = ws[(b * 9 + kk) * HW + pos];
    float sx = ws[WS_N + (b * 9 + kk) * HW + pos];
    float m  = ws[2 * WS_N + (b * 9 + kk) * HW + pos];
    float y0f = floorf(sy), x0f = floorf(sx);
    s_y0[tid] = (int)y0f; s_x0[tid] = (int)x0f;
    s_wy[tid] = sy - y0f; s_wx[tid] = sx - x0f; s_m[tid] = m;
  }
  __syncthreads();

  const int i  = tid & 63;   // co group: co = 4i+a
  const int jj = tid >> 6;   // pos group: p = 4jj+e
  float acc[4][4] = {{0.f}};
  const float* xb = x + (size_t)b * CIN * HW;

  for (int c0 = 0; c0 < CIN; c0 += CC) {
    // ---- stage weights: thread tid == co; 9 x float4 covering c0..c0+3 x 9 taps
    {
      const float4* wg = (const float4*)(w_dcn + (size_t)tid * KTOT + c0 * 9);
#pragma unroll
      for (int q = 0; q < 9; ++q) {
        float4 f = wg[q];
        w_lds[(4 * q + 0) * 256 + tid] = f.x;
        w_lds[(4 * q + 1) * 256 + tid] = f.y;
        w_lds[(4 * q + 2) * 256 + tid] = f.z;
        w_lds[(4 * q + 3) * 256 + tid] = f.w;
      }
    }
    // ---- gather v: CC*144 = 576 items
    for (int it = tid; it < CC * 144; it += 256) {
      int cl = it / 144, rem = it - cl * 144;
      int y0 = s_y0[rem], x0 = s_x0[rem];
      float wy = s_wy[rem], wx = s_wx[rem], m = s_m[rem];
      const float* xc = xb + (c0 + cl) * HW;
      bool yok0 = (unsigned)y0 < 64u,  yok1 = (unsigned)(y0 + 1) < 64u;
      bool xok0 = (unsigned)x0 < 64u,  xok1 = (unsigned)(x0 + 1) < 64u;
      float v00 = (yok0 && xok0) ? xc[y0 * 64 + x0]           : 0.f;
      float v01 = (yok0 && xok1) ? xc[y0 * 64 + x0 + 1]       : 0.f;
      float v10 = (yok1 && xok0) ? xc[(y0 + 1) * 64 + x0]     : 0.f;
      float v11 = (yok1 && xok1) ? xc[(y0 + 1) * 64 + x0 + 1] : 0.f;
      float v = ((1.f - wy) * (1.f - wx) * v00 + (1.f - wy) * wx * v01 +
                 wy * (1.f - wx) * v10 + wy * wx * v11) * m;
      v_lds[it] = v;   // [cl*9+kk][p] == it
    }
    __syncthreads();

    // ---- compute: 36 k-steps, 16 FMA each
#pragma unroll
    for (int kidx = 0; kidx < 36; ++kidx) {
      float4 wv = *(const float4*)&w_lds[kidx * 256 + 4 * i];
      float4 vv = *(const float4*)&v_lds[kidx * 16 + 4 * jj];
      acc[0][0] = fmaf(wv.x, vv.x, acc[0][0]);
      acc[0][1] = fmaf(wv.x, vv.y, acc[0][1]);
      acc[0][2] = fmaf(wv.x, vv.z, acc[0][2]);
      acc[0][3] = fmaf(wv.x, vv.w, acc[0][3]);
      acc[1][0] = fmaf(wv.y, vv.x, acc[1][0]);
      acc[1][1] = fmaf(wv.y, vv.y, acc[1][1]);
      acc[1][2] = fmaf(wv.y, vv.z, acc[1][2]);
      acc[1][3] = fmaf(wv.y, vv.w, acc[1][3]);
      acc[2][0] = fmaf(wv.z, vv.x, acc[2][0]);
      acc[2][1] = fmaf(wv.z, vv.y, acc[2][1]);
      acc[2][2] = fmaf(wv.z, vv.z, acc[2][2]);
      acc[2][3] = fmaf(wv.z, vv.w, acc[2][3]);
      acc[3][0] = fmaf(wv.w, vv.x, acc[3][0]);
      acc[3][1] = fmaf(wv.w, vv.y, acc[3][1]);
      acc[3][2] = fmaf(wv.w, vv.z, acc[3][2]);
      acc[3][3] = fmaf(wv.w, vv.w, acc[3][3]);
    }
    __syncthreads();
  }

  // ---- epilogue
#pragma unroll
  for (int a = 0; a < 4; ++a) {
    int co = 4 * i + a;
    float bias = b_dcn[co];
    float4 r;
    r.x = acc[a][0] + bias; r.y = acc[a][1] + bias;
    r.z = acc[a][2] + bias; r.w = acc[a][3] + bias;
    *(float4*)&out[((size_t)b * COUT + co) * HW + pos0 + 4 * jj] = r;
  }
}

extern "C" void kernel_launch(void* const* d_in, const int* in_sizes, int n_in,
                              void* d_out, int out_size, void* d_ws, size_t ws_size,
                              hipStream_t stream) {
  const float* x     = (const float*)d_in[0];
  const float* w_off = (const float*)d_in[1];
  const float* b_off = (const float*)d_in[2];
  const float* w_dcn = (const float*)d_in[3];
  const float* b_dcn = (const float*)d_in[4];
  float* out = (float*)d_out;
  float* ws  = (float*)d_ws;

  offconv_kernel<<<(BB * KKT * HW) / 256, 256, 0, stream>>>(x, w_off, b_off, ws);
  dcn_kernel<<<BB * (HW / 16), 256, 0, stream>>>(x, w_dcn, b_dcn, ws, out);
}

// Round 2
// 436.704 us; speedup vs baseline: 2.4564x; 2.4564x over previous
//
#include <hip/hip_runtime.h>
#include <math.h>

#define BB 8
#define CIN 256
#define HW 4096
#define COUT 256
#define KKT 9
#define KTOT 2304          // CIN*9
#define WS_N (BB*KKT*HW)   // 294912 floats per param array

typedef __bf16 bf16;
typedef __attribute__((ext_vector_type(8))) __bf16 bf16x8;
typedef __attribute__((ext_vector_type(4))) __bf16 bf16x4;
typedef __attribute__((ext_vector_type(4))) float f32x4;

// ---------------- Kernel 1: offset conv (256->27) + transform ----------------
__global__ __launch_bounds__(256) void offconv_kernel(
    const float* __restrict__ x, const float* __restrict__ w_off,
    const float* __restrict__ b_off, float* __restrict__ ws)
{
  __shared__ float w_s[3 * KTOT];

  const int tid = threadIdx.x;
  const int g0  = blockIdx.x * 256;
  const int t   = g0 >> 12;
  const int jg  = t % 9;
  const int b   = t / 9;
  const int pos = (g0 & 4095) + tid;
  const int ho  = pos >> 6, wo = pos & 63;

  for (int q = tid; q < 3 * KTOT; q += 256) {
    int jj = q / KTOT, r = q - jj * KTOT;
    w_s[q] = w_off[(jg + 9 * jj) * KTOT + r];
  }
  __syncthreads();

  float a0 = b_off[jg], a1 = b_off[jg + 9], a2 = b_off[jg + 18];
  const float* xb = x + (size_t)b * CIN * HW;

  for (int c = 0; c < CIN; ++c) {
    const float* xc = xb + c * HW;
    const float* wc = w_s + c * 9;
#pragma unroll
    for (int t9 = 0; t9 < 9; ++t9) {
      int ky = t9 / 3, kx = t9 - 3 * ky;
      int yy = ho - 1 + ky, xx = wo - 1 + kx;
      bool ok = ((unsigned)yy < 64u) && ((unsigned)xx < 64u);
      float xv = ok ? xc[yy * 64 + xx] : 0.0f;
      a0 = fmaf(wc[t9],            xv, a0);
      a1 = fmaf(wc[KTOT + t9],     xv, a1);
      a2 = fmaf(wc[2 * KTOT + t9], xv, a2);
    }
  }

  {
    int kk = jg >> 1;
    if ((jg & 1) == 0) ws[(b * 9 + kk) * HW + pos] = a0 + (float)(ho - 1 + kk / 3);
    else               ws[WS_N + (b * 9 + kk) * HW + pos] = a0 + (float)(wo - 1 + kk % 3);
  }
  {
    int j = jg + 9;
    int kk = j >> 1;
    if ((j & 1) == 0) ws[(b * 9 + kk) * HW + pos] = a1 + (float)(ho - 1 + kk / 3);
    else               ws[WS_N + (b * 9 + kk) * HW + pos] = a1 + (float)(wo - 1 + kk % 3);
  }
  ws[2 * WS_N + (b * 9 + jg) * HW + pos] = 1.0f / (1.0f + expf(-a2));
}

// ---------------- Kernel 1b: w_dcn fp32 -> bf16 ----------------
__global__ __launch_bounds__(256) void wconv_kernel(
    const float* __restrict__ w, bf16* __restrict__ o)
{
  int i = (blockIdx.x * 256 + threadIdx.x) * 4;
  float4 f = *(const float4*)(w + i);
  bf16x4 r;
  r.x = (bf16)f.x; r.y = (bf16)f.y; r.z = (bf16)f.z; r.w = (bf16)f.w;
  *(bf16x4*)(o + i) = r;
}

// ---------------- Kernel 2: bilinear gather + MFMA GEMM ----------------
// 512 threads (8 waves), tile 256 co x 64 pos, K-step 32.
// wave (wr,wc): wr in [0,4) -> 64-co quarter, wc in [0,2) -> 32-pos half.
#define KSTEP 32
#define NK (KTOT / KSTEP)   // 72
#define AP 40               // padded row length (elements) for A/B LDS

__global__ __launch_bounds__(512) void dcn_mfma_kernel(
    const float* __restrict__ x, const bf16* __restrict__ w16,
    const float* __restrict__ b_dcn, const float* __restrict__ ws,
    float* __restrict__ out)
{
  __shared__ bf16 A_lds[256 * AP];     // [co][k] rows padded to 80B
  __shared__ bf16 Bv_lds[64 * AP];     // [pos][k] rows padded to 80B
  __shared__ float4 P0[576];           // packed corner indices (bitcast int)
  __shared__ float4 P1[576];           // corner weights (mask+validity folded)

  const int tid  = threadIdx.x;
  const int b    = blockIdx.x >> 6;
  const int pos0 = (blockIdx.x & 63) * 64;

  // ---- per-(kk,p) bilinear params
  for (int t = tid; t < 576; t += 512) {
    int kk = t >> 6, p = t & 63;
    int pos = pos0 + p;
    float sy = ws[(b * 9 + kk) * HW + pos];
    float sx = ws[WS_N + (b * 9 + kk) * HW + pos];
    float m  = ws[2 * WS_N + (b * 9 + kk) * HW + pos];
    float y0f = floorf(sy), x0f = floorf(sx);
    int y0 = (int)y0f, x0 = (int)x0f;
    float wy = sy - y0f, wx = sx - x0f;
    int iy0 = min(max(y0, 0), 63),     iy1 = min(max(y0 + 1, 0), 63);
    int ix0 = min(max(x0, 0), 63),     ix1 = min(max(x0 + 1, 0), 63);
    float vy0 = (y0 >= 0 && y0 <= 63) ? 1.f : 0.f;
    float vy1 = (y0 >= -1 && y0 <= 62) ? 1.f : 0.f;
    float vx0 = (x0 >= 0 && x0 <= 63) ? 1.f : 0.f;
    float vx1 = (x0 >= -1 && x0 <= 62) ? 1.f : 0.f;
    float w00 = (1.f - wy) * (1.f - wx) * m * vy0 * vx0;
    float w01 = (1.f - wy) * wx        * m * vy0 * vx1;
    float w10 = wy * (1.f - wx)        * m * vy1 * vx0;
    float w11 = wy * wx                * m * vy1 * vx1;
    P0[t] = make_float4(__int_as_float(iy0 * 64 + ix0), __int_as_float(iy0 * 64 + ix1),
                        __int_as_float(iy1 * 64 + ix0), __int_as_float(iy1 * 64 + ix1));
    P1[t] = make_float4(w00, w01, w10, w11);
  }
  __syncthreads();

  const int lane = tid & 63;
  const int wid  = tid >> 6;
  const int wr   = wid >> 1;
  const int wc   = wid & 1;
  const int lm   = lane & 15;
  const int lk   = lane >> 4;

  f32x4 acc[4][2];
#pragma unroll
  for (int a = 0; a < 4; ++a)
#pragma unroll
    for (int c = 0; c < 2; ++c)
      acc[a][c] = (f32x4){0.f, 0.f, 0.f, 0.f};

  const float* xb = x + (size_t)b * CIN * HW;
  // A-stage ids: thread = (co, k-half)
  const int aco = tid & 255;
  const int ah  = tid >> 8;
  const bf16* wrow = w16 + (size_t)aco * KTOT + ah * 16;
  // B-gather ids: thread = (pos p, 4-k group g)
  const int gp = tid & 63;
  const int gg = tid >> 6;

  for (int ks = 0; ks < NK; ++ks) {
    const int k0 = ks * KSTEP;
    // ---- stage A: 16 bf16 (32B) per thread
    {
      uint4 a0 = *(const uint4*)(wrow + k0);
      uint4 a1 = *(const uint4*)(wrow + k0 + 8);
      *(uint4*)&A_lds[aco * AP + ah * 16]     = a0;
      *(uint4*)&A_lds[aco * AP + ah * 16 + 8] = a1;
    }
    // ---- gather V: 4 elements (k0+gg*4 .. +3) x pos gp
    {
      int kL = k0 + gg * 4;          // wave-uniform
      int c  = kL / 9;
      int kk = kL - c * 9;
      const float* xc = xb + (size_t)c * HW;
      bf16x4 vv;
#pragma unroll
      for (int e = 0; e < 4; ++e) {
        float4 pi = P0[kk * 64 + gp];
        float4 pw = P1[kk * 64 + gp];
        float v = pw.x * xc[__float_as_int(pi.x)]
                + pw.y * xc[__float_as_int(pi.y)]
                + pw.z * xc[__float_as_int(pi.z)]
                + pw.w * xc[__float_as_int(pi.w)];
        vv[e] = (bf16)v;
        if (++kk == 9) { kk = 0; xc += HW; }
      }
      *(bf16x4*)&Bv_lds[gp * AP + gg * 4] = vv;
    }
    __syncthreads();

    // ---- fragments + MFMA
    bf16x8 af[4], bfr[2];
#pragma unroll
    for (int fr = 0; fr < 4; ++fr)
      af[fr] = *(const bf16x8*)&A_lds[(wr * 64 + fr * 16 + lm) * AP + lk * 8];
#pragma unroll
    for (int fc = 0; fc < 2; ++fc)
      bfr[fc] = *(const bf16x8*)&Bv_lds[(wc * 32 + fc * 16 + lm) * AP + lk * 8];
#pragma unroll
    for (int fr = 0; fr < 4; ++fr)
#pragma unroll
      for (int fc = 0; fc < 2; ++fc)
        acc[fr][fc] = __builtin_amdgcn_mfma_f32_16x16x32_bf16(af[fr], bfr[fc], acc[fr][fc], 0, 0, 0);
    __syncthreads();
  }

  // ---- epilogue: bias + store (C/D: col=lane&15, row=(lane>>4)*4+reg)
  const int pbase = pos0 + wc * 32;
#pragma unroll
  for (int fr = 0; fr < 4; ++fr) {
#pragma unroll
    for (int r = 0; r < 4; ++r) {
      int co = wr * 64 + fr * 16 + lk * 4 + r;
      float bias = b_dcn[co];
      float* orow = out + ((size_t)b * COUT + co) * HW + pbase;
#pragma unroll
      for (int fc = 0; fc < 2; ++fc)
        orow[fc * 16 + lm] = acc[fr][fc][r] + bias;
    }
  }
}

extern "C" void kernel_launch(void* const* d_in, const int* in_sizes, int n_in,
                              void* d_out, int out_size, void* d_ws, size_t ws_size,
                              hipStream_t stream) {
  const float* x     = (const float*)d_in[0];
  const float* w_off = (const float*)d_in[1];
  const float* b_off = (const float*)d_in[2];
  const float* w_dcn = (const float*)d_in[3];
  const float* b_dcn = (const float*)d_in[4];
  float* out = (float*)d_out;
  float* ws  = (float*)d_ws;
  bf16* w16  = (bf16*)(ws + 3 * WS_N);

  offconv_kernel<<<(BB * KKT * HW) / 256, 256, 0, stream>>>(x, w_off, b_off, ws);
  wconv_kernel<<<(COUT * KTOT) / 1024, 256, 0, stream>>>(w_dcn, w16);
  dcn_mfma_kernel<<<BB * (HW / 64), 512, 0, stream>>>(x, w16, b_dcn, ws, out);
}